// Round 1
// 3298.780 us; speedup vs baseline: 1.1157x; 1.1157x over previous
//
#include <hip/hip_runtime.h>
#include <hip/hip_bf16.h>
#include <math.h>

typedef __attribute__((ext_vector_type(8))) short bf16x8;
typedef __attribute__((ext_vector_type(4))) float f32x4;

constexpr int NPTS = 65536;
constexpr int ENC  = 512;
constexpr int P    = 4096;
constexpr int JD   = 1024;   // 2*ENC
constexpr int ID   = 8192;   // 2*P
constexpr int CH   = 8192;   // point chunk
constexpr int NCH  = NPTS / CH;
constexpr int LDK  = 8192;   // k-stride (elements) of all GEMM operand rows

constexpr float INV_R   = 20.0f;                  // 1/0.05
constexpr float INV2PI  = 0.15915494309189535f;
constexpr float SQRT_D  = 22.627416997969522f;    // sqrt(512)

__device__ __forceinline__ unsigned short f2bf(float f) {
    unsigned int u = __float_as_uint(f);
    u = (u + 0x7FFFu + ((u >> 16) & 1u)) >> 16;
    return (unsigned short)u;
}

// phases are up to ~±350 revolutions: must fract-reduce before v_sin/v_cos
__device__ __forceinline__ void sincos_rev(float p, float* s, float* c) {
    float r = p * INV2PI;
    r = r - floorf(r);                 // [0,1)
    *s = __builtin_amdgcn_sinf(r);     // sin(2*pi*r)
    *c = __builtin_amdgcn_cosf(r);
}

__device__ __forceinline__ void gload16(const void* g, void* l) {
    __builtin_amdgcn_global_load_lds(
        (const __attribute__((address_space(1))) unsigned int*)g,
        (__attribute__((address_space(3))) unsigned int*)l, 16, 0, 0);
}

// ---------------- gen transposed e-matrices (phase A) ----------------
// eAT [1024][CH], eBT [8192][CH]; each thread: one row r, two consecutive points
__global__ __launch_bounds__(256)
void gen_t(const float* __restrict__ pts, const float* __restrict__ A,
           const float* __restrict__ B, unsigned short* __restrict__ eAT,
           unsigned short* __restrict__ eBT, int n0) {
    int idx = blockIdx.x * 256 + threadIdx.x;
    int nh  = idx & (CH / 2 - 1);      // 4096 pairs
    int r   = idx >> 12;               // row in [0, 4608): first 512 = A rows
    int nl  = nh * 2;
    int n   = n0 + nl;
    float x0a = pts[n * 3 + 0], x1a = pts[n * 3 + 1], x2a = pts[n * 3 + 2];
    float x0b = pts[n * 3 + 3], x1b = pts[n * 3 + 4], x2b = pts[n * 3 + 5];
    float w0, w1, w2;
    unsigned short *dc, *dsn;
    if (r < ENC) {
        w0 = A[r]; w1 = A[ENC + r]; w2 = A[2 * ENC + r];
        dc  = eAT + (size_t)r * CH + nl;
        dsn = eAT + (size_t)(r + ENC) * CH + nl;
    } else {
        int i = r - ENC;
        w0 = B[i]; w1 = B[P + i]; w2 = B[2 * P + i];
        dc  = eBT + (size_t)i * CH + nl;
        dsn = eBT + (size_t)(i + P) * CH + nl;
    }
    float pa = (x0a * w0 + x1a * w1 + x2a * w2) * INV_R;
    float pb = (x0b * w0 + x1b * w1 + x2b * w2) * INV_R;
    float sa, ca, sb, cb;
    sincos_rev(pa, &sa, &ca);
    sincos_rev(pb, &sb, &cb);
    ushort2 vc; vc.x = f2bf(ca); vc.y = f2bf(cb);
    ushort2 vs; vs.x = f2bf(sa); vs.y = f2bf(sb);
    *(ushort2*)dc  = vc;
    *(ushort2*)dsn = vs;
}

// ---------------- gen eB row-major (phase C) ----------------
// eB [CH][8192]; thread: one point, two consecutive i
__global__ __launch_bounds__(256)
void gen_b(const float* __restrict__ pts, const float* __restrict__ B,
           unsigned short* __restrict__ eB, int n0) {
    int idx = blockIdx.x * 256 + threadIdx.x;
    int ih = idx & 2047;
    int ln = idx >> 11;
    int i  = ih * 2;
    int n  = n0 + ln;
    float x0 = pts[n * 3 + 0], x1 = pts[n * 3 + 1], x2 = pts[n * 3 + 2];
    float p0 = (x0 * B[i]     + x1 * B[P + i]     + x2 * B[2 * P + i])     * INV_R;
    float p1 = (x0 * B[i + 1] + x1 * B[P + i + 1] + x2 * B[2 * P + i + 1]) * INV_R;
    float s0, c0, s1, c1;
    sincos_rev(p0, &s0, &c0);
    sincos_rev(p1, &s1, &c1);
    ushort2 vc; vc.x = f2bf(c0); vc.y = f2bf(c1);
    ushort2 vs; vs.x = f2bf(s0); vs.y = f2bf(s1);
    *(ushort2*)(eB + (size_t)ln * ID + i)     = vc;
    *(ushort2*)(eB + (size_t)ln * ID + P + i) = vs;
}

// ---------------- GEMM: C[m][n] (+)= sum_k Ag[m][k]*Bg[n][k] ----------------
// BMxBN tile, 512 threads = 8 waves of 64x64, BK=64, triple-buffered LDS
// (prefetch depth 2 -> counted vmcnt(6), never 0 in steady state),
// 2 phases/K-tile {8 ds_read_b128 || 3 global_load_lds -> bar -> lgkm(0) ->
// setprio(1) 16 MFMA setprio(0) -> bar}, XOR-16B-slot swizzle, XCD swizzle.
template <int BM, int BN, int K, bool ACCUM>
__global__ __launch_bounds__(512, 2)
void gemm_nt(const unsigned short* __restrict__ Ag,
             const unsigned short* __restrict__ Bg,
             float* __restrict__ C, int ldc, int beta) {
    constexpr int BSZ = (BM + BN) * 64;          // elements per K-tile buffer
    constexpr int NA  = BM / 64;                 // A gload issues per K-tile
    constexpr int NB  = BN / 64;                 // B gload issues per K-tile
    constexpr int NT  = K / 64;
    static_assert(NA + NB == 6, "6 issues/K-tile assumed by vmcnt(6)");
    __shared__ __align__(16) unsigned short lds[3 * BSZ];   // 144 KiB

    const int tid  = threadIdx.x;
    const int wave = tid >> 6, lane = tid & 63;
    const int mr = lane & 15, q = lane >> 4;
    const int srow = tid >> 3, sslot = tid & 7;       // staging row/slot
    const int wm = (BM >= BN) ? (wave >> 1) * 64 : (wave & 1) * 64;
    const int wn = (BM >= BN) ? (wave & 1) * 64 : (wave >> 1) * 64;

    // XCD-chunked block swizzle (nwg == 256, divisible by 8 -> bijective)
    const int gx   = gridDim.x;
    const int nwg  = gx * gridDim.y;
    const int flat = blockIdx.y * gx + blockIdx.x;
    const int swz  = (flat & 7) * (nwg >> 3) + (flat >> 3);
    const int m0   = (swz % gx) * BM;
    const int n0   = (swz / gx) * BN;

    const char* aG = (const char*)Ag;
    const char* bG = (const char*)Bg;
    const int ssw = (sslot ^ (srow & 7)) * 16;        // pre-swizzled src slot
    size_t aoff[NA], boff[NB];
#pragma unroll
    for (int j = 0; j < NA; ++j)
        aoff[j] = (size_t)(m0 + j * 64 + srow) * (LDK * 2) + ssw;
#pragma unroll
    for (int j = 0; j < NB; ++j)
        boff[j] = (size_t)(n0 + j * 64 + srow) * (LDK * 2) + ssw;

    unsigned short* bufC  = lds;
    unsigned short* bufN  = lds + BSZ;
    unsigned short* bufN2 = lds + 2 * BSZ;

    // issue idx in [0,6): first NA are A-halves, rest B-halves
    auto stage = [&](int idx, unsigned short* buf, size_t kB) {
        if (idx < NA)
            gload16(aG + aoff[idx] + kB, buf + idx * 4096 + wave * 512);
        else
            gload16(bG + boff[idx - NA] + kB,
                    buf + BM * 64 + (idx - NA) * 4096 + wave * 512);
    };

    f32x4 acc[4][4];
#pragma unroll
    for (int a = 0; a < 4; ++a)
#pragma unroll
        for (int b = 0; b < 4; ++b) acc[a][b] = (f32x4){0.f, 0.f, 0.f, 0.f};

    // prologue: tiles 0 and 1 in flight, wait tile 0 only (vmcnt(6))
#pragma unroll
    for (int i = 0; i < 6; ++i) stage(i, bufC, 0);
#pragma unroll
    for (int i = 0; i < 6; ++i) stage(i, bufN, 128);
    asm volatile("s_waitcnt vmcnt(6)" ::: "memory");
    __builtin_amdgcn_s_barrier();
    __builtin_amdgcn_sched_barrier(0);

    size_t kPre = 256;                 // byte k-offset of tile kt+2
#pragma unroll 1
    for (int kt = 0; kt < NT; ++kt) {
        const bool pf = (kt + 2 < NT);
        // ---------------- phase 0: kk = 0 ----------------
        {
            bf16x8 af[4], bfr[4];
#pragma unroll
            for (int mi = 0; mi < 4; ++mi) {
                int m = wm + mi * 16 + mr;
                af[mi] = *(const bf16x8*)(bufC + m * 64 + ((q ^ (m & 7)) * 8));
            }
#pragma unroll
            for (int ni = 0; ni < 4; ++ni) {
                int n = wn + ni * 16 + mr;
                bfr[ni] = *(const bf16x8*)(bufC + BM * 64 + n * 64 +
                                           ((q ^ (n & 7)) * 8));
            }
            if (pf) {
#pragma unroll
                for (int i = 0; i < 3; ++i) stage(i, bufN2, kPre);
            }
            __builtin_amdgcn_s_barrier();
            asm volatile("s_waitcnt lgkmcnt(0)" ::: "memory");
            __builtin_amdgcn_s_setprio(1);
#pragma unroll
            for (int mi = 0; mi < 4; ++mi)
#pragma unroll
                for (int ni = 0; ni < 4; ++ni)
                    acc[mi][ni] = __builtin_amdgcn_mfma_f32_16x16x32_bf16(
                        af[mi], bfr[ni], acc[mi][ni], 0, 0, 0);
            __builtin_amdgcn_s_setprio(0);
            __builtin_amdgcn_s_barrier();
        }
        // ---------------- phase 1: kk = 1 ----------------
        {
            bf16x8 af[4], bfr[4];
#pragma unroll
            for (int mi = 0; mi < 4; ++mi) {
                int m = wm + mi * 16 + mr;
                af[mi] = *(const bf16x8*)(bufC + m * 64 +
                                          (((4 + q) ^ (m & 7)) * 8));
            }
#pragma unroll
            for (int ni = 0; ni < 4; ++ni) {
                int n = wn + ni * 16 + mr;
                bfr[ni] = *(const bf16x8*)(bufC + BM * 64 + n * 64 +
                                           (((4 + q) ^ (n & 7)) * 8));
            }
            if (pf) {
#pragma unroll
                for (int i = 3; i < 6; ++i) stage(i, bufN2, kPre);
            }
            __builtin_amdgcn_s_barrier();
            asm volatile("s_waitcnt lgkmcnt(0)" ::: "memory");
            __builtin_amdgcn_s_setprio(1);
#pragma unroll
            for (int mi = 0; mi < 4; ++mi)
#pragma unroll
                for (int ni = 0; ni < 4; ++ni)
                    acc[mi][ni] = __builtin_amdgcn_mfma_f32_16x16x32_bf16(
                        af[mi], bfr[ni], acc[mi][ni], 0, 0, 0);
            __builtin_amdgcn_s_setprio(0);
            // end-of-tile wait: next tile's loads must have landed,
            // tile kt+2's 6 loads stay in flight (counted, never 0 mid-loop)
            if (pf)                    asm volatile("s_waitcnt vmcnt(6)" ::: "memory");
            else if (kt + 1 < NT)      asm volatile("s_waitcnt vmcnt(0)" ::: "memory");
            __builtin_amdgcn_s_barrier();
            __builtin_amdgcn_sched_barrier(0);
        }
        unsigned short* t = bufC; bufC = bufN; bufN = bufN2; bufN2 = t;
        kPre += 128;
    }

    // C/D layout: col = lane&15, row = (lane>>4)*4 + reg
#pragma unroll
    for (int mi = 0; mi < 4; ++mi)
#pragma unroll
        for (int ni = 0; ni < 4; ++ni)
#pragma unroll
            for (int r = 0; r < 4; ++r) {
                int m = m0 + wm + mi * 16 + q * 4 + r;
                int n = n0 + wn + ni * 16 + mr;
                size_t off = (size_t)m * ldc + n;
                float v = acc[mi][ni][r];
                if (ACCUM) { if (beta) v += C[off]; }
                C[off] = v;
            }
}

// ---------------- MT fp32 -> bf16 ----------------
__global__ __launch_bounds__(256)
void cvt(const float* __restrict__ src, unsigned short* __restrict__ dst) {
    int idx = blockIdx.x * 256 + threadIdx.x;
    float4 v = ((const float4*)src)[idx];
    ushort4 o;
    o.x = f2bf(v.x); o.y = f2bf(v.y); o.z = f2bf(v.z); o.w = f2bf(v.w);
    ((ushort4*)dst)[idx] = o;
}

// ---------------- epilogue: re/im, row norm, scale (in place on d_out) ----
__global__ __launch_bounds__(256)
void epi(float* __restrict__ out, const float* __restrict__ pts,
         const float* __restrict__ A) {
    int n = blockIdx.x;
    int t = threadIdx.x;
    float x0 = pts[n * 3 + 0], x1 = pts[n * 3 + 1], x2 = pts[n * 3 + 2];
    float* row = out + (size_t)n * JD;
    float reA[2], imA[2];
    float ssum = 0.f;
#pragma unroll
    for (int u = 0; u < 2; ++u) {
        int j = t + u * 256;
        float pa = (x0 * A[j] + x1 * A[ENC + j] + x2 * A[2 * ENC + j]) * INV_R;
        float s, c;
        sincos_rev(pa, &s, &c);
        float gc = row[j], gs = row[ENC + j];
        float re = gc * c + gs * s;
        float im = gs * c - gc * s;
        reA[u] = re; imA[u] = im;
        ssum += re * re + im * im;
    }
#pragma unroll
    for (int off = 32; off > 0; off >>= 1) ssum += __shfl_down(ssum, off);
    __shared__ float red[4];
    if ((t & 63) == 0) red[t >> 6] = ssum;
    __syncthreads();
    float tot = red[0] + red[1] + red[2] + red[3];
    float scale = SQRT_D / sqrtf(tot);
#pragma unroll
    for (int u = 0; u < 2; ++u) {
        int j = t + u * 256;
        row[j]       = reA[u] * scale;
        row[ENC + j] = imA[u] * scale;
    }
}

extern "C" void kernel_launch(void* const* d_in, const int* in_sizes, int n_in,
                              void* d_out, int out_size, void* d_ws, size_t ws_size,
                              hipStream_t stream) {
    const float* pts = (const float*)d_in[0];
    const float* A   = (const float*)d_in[1];
    const float* B   = (const float*)d_in[2];
    float* out = (float*)d_out;
    char* ws = (char*)d_ws;

    // ws layout (192 MiB total):
    //   [0, 16M)          eAT  [1024][8192] bf16   (phase A)  / eB [8192][8192] (phase C, spans both)
    //   [16M, 151M)       eBT  [8192][8192] bf16   (phase A)
    //   [151M, 183M)      MTf  [1024][8192] fp32
    //   [183M, 199M)      MTb  [1024][8192] bf16
    unsigned short* eAT = (unsigned short*)ws;
    unsigned short* eBT = (unsigned short*)(ws + (size_t)JD * CH * 2);
    unsigned short* eBw = (unsigned short*)ws;
    size_t offMT = (size_t)(JD + ID) * CH * 2;
    float* MTf = (float*)(ws + offMT);
    unsigned short* MTb = (unsigned short*)(ws + offMT + (size_t)JD * ID * 4);

    for (int c = 0; c < NCH; ++c) {
        gen_t<<<dim3(73728), 256, 0, stream>>>(pts, A, B, eAT, eBT, c * CH);
        // MT[j][i] += eAT[j][:] . eBT[i][:]   (M=1024, N=8192 -> 8x32=256 WGs)
        gemm_nt<128, 256, CH, true><<<dim3(8, 32), 512, 0, stream>>>(
            eAT, eBT, MTf, ID, c);
    }
    cvt<<<dim3(8192), 256, 0, stream>>>(MTf, MTb);
    for (int c = 0; c < NCH; ++c) {
        gen_b<<<dim3(65536), 256, 0, stream>>>(pts, B, eBw, c * CH);
        // G[ln][j] = eB[ln][:] . MTb[j][:]    (M=8192, N=1024 -> 32x8=256 WGs)
        gemm_nt<256, 128, ID, false><<<dim3(32, 8), 512, 0, stream>>>(
            eBw, MTb, out + (size_t)c * CH * JD, JD, 0);
    }
    epi<<<dim3(NPTS), 256, 0, stream>>>(out, pts, A);
}

// Round 3
// 3277.822 us; speedup vs baseline: 1.1229x; 1.0064x over previous
//
#include <hip/hip_runtime.h>
#include <hip/hip_bf16.h>
#include <math.h>

typedef __attribute__((ext_vector_type(8))) short bf16x8;
typedef __attribute__((ext_vector_type(4))) float f32x4;

constexpr int NPTS = 65536;
constexpr int ENC  = 512;
constexpr int P    = 4096;
constexpr int JD   = 1024;   // 2*ENC
constexpr int ID   = 8192;   // 2*P
constexpr int CH   = 8192;   // point chunk
constexpr int NCH  = NPTS / CH;
constexpr int LDK  = 8192;   // k-stride (elements) of all GEMM operand rows

constexpr float INV_R   = 20.0f;                  // 1/0.05
constexpr float INV2PI  = 0.15915494309189535f;
constexpr float SQRT_D  = 22.627416997969522f;    // sqrt(512)

__device__ __forceinline__ unsigned short f2bf(float f) {
    unsigned int u = __float_as_uint(f);
    u = (u + 0x7FFFu + ((u >> 16) & 1u)) >> 16;
    return (unsigned short)u;
}

// phases are up to ~±350 revolutions: must fract-reduce before v_sin/v_cos
__device__ __forceinline__ void sincos_rev(float p, float* s, float* c) {
    float r = p * INV2PI;
    r = r - floorf(r);                 // [0,1)
    *s = __builtin_amdgcn_sinf(r);     // sin(2*pi*r)
    *c = __builtin_amdgcn_cosf(r);
}

__device__ __forceinline__ void gload16(const void* g, void* l) {
    __builtin_amdgcn_global_load_lds(
        (const __attribute__((address_space(1))) unsigned int*)g,
        (__attribute__((address_space(3))) unsigned int*)l, 16, 0, 0);
}

// ---------------- gen transposed e-matrices (phase A) ----------------
// eAT [1024][CH], eBT [8192][CH]; each thread: one row r, two consecutive points
__global__ __launch_bounds__(256)
void gen_t(const float* __restrict__ pts, const float* __restrict__ A,
           const float* __restrict__ B, unsigned short* __restrict__ eAT,
           unsigned short* __restrict__ eBT, int n0) {
    int idx = blockIdx.x * 256 + threadIdx.x;
    int nh  = idx & (CH / 2 - 1);      // 4096 pairs
    int r   = idx >> 12;               // row in [0, 4608): first 512 = A rows
    int nl  = nh * 2;
    int n   = n0 + nl;
    float x0a = pts[n * 3 + 0], x1a = pts[n * 3 + 1], x2a = pts[n * 3 + 2];
    float x0b = pts[n * 3 + 3], x1b = pts[n * 3 + 4], x2b = pts[n * 3 + 5];
    float w0, w1, w2;
    unsigned short *dc, *dsn;
    if (r < ENC) {
        w0 = A[r]; w1 = A[ENC + r]; w2 = A[2 * ENC + r];
        dc  = eAT + (size_t)r * CH + nl;
        dsn = eAT + (size_t)(r + ENC) * CH + nl;
    } else {
        int i = r - ENC;
        w0 = B[i]; w1 = B[P + i]; w2 = B[2 * P + i];
        dc  = eBT + (size_t)i * CH + nl;
        dsn = eBT + (size_t)(i + P) * CH + nl;
    }
    float pa = (x0a * w0 + x1a * w1 + x2a * w2) * INV_R;
    float pb = (x0b * w0 + x1b * w1 + x2b * w2) * INV_R;
    float sa, ca, sb, cb;
    sincos_rev(pa, &sa, &ca);
    sincos_rev(pb, &sb, &cb);
    ushort2 vc; vc.x = f2bf(ca); vc.y = f2bf(cb);
    ushort2 vs; vs.x = f2bf(sa); vs.y = f2bf(sb);
    *(ushort2*)dc  = vc;
    *(ushort2*)dsn = vs;
}

// ---------------- gen eB row-major (phase C) ----------------
// eB [CH][8192]; thread: one point, two consecutive i
__global__ __launch_bounds__(256)
void gen_b(const float* __restrict__ pts, const float* __restrict__ B,
           unsigned short* __restrict__ eB, int n0) {
    int idx = blockIdx.x * 256 + threadIdx.x;
    int ih = idx & 2047;
    int ln = idx >> 11;
    int i  = ih * 2;
    int n  = n0 + ln;
    float x0 = pts[n * 3 + 0], x1 = pts[n * 3 + 1], x2 = pts[n * 3 + 2];
    float p0 = (x0 * B[i]     + x1 * B[P + i]     + x2 * B[2 * P + i])     * INV_R;
    float p1 = (x0 * B[i + 1] + x1 * B[P + i + 1] + x2 * B[2 * P + i + 1]) * INV_R;
    float s0, c0, s1, c1;
    sincos_rev(p0, &s0, &c0);
    sincos_rev(p1, &s1, &c1);
    ushort2 vc; vc.x = f2bf(c0); vc.y = f2bf(c1);
    ushort2 vs; vs.x = f2bf(s0); vs.y = f2bf(s1);
    *(ushort2*)(eB + (size_t)ln * ID + i)     = vc;
    *(ushort2*)(eB + (size_t)ln * ID + P + i) = vs;
}

// ---------------- GEMM: C[m][n] (+)= sum_k Ag[m][k]*Bg[n][k] ----------------
// BMxBN tile, 512 threads = 8 waves of 64x64, BK=64, triple-buffered LDS
// (prefetch depth 2 -> counted vmcnt(6), never 0 in steady state).
// ONE fence-free region per K-tile: 16 ds_read, then 6 gload (proven R1
// order: ds_read before gload_lds so no conservative vmcnt blocks the
// reads), then 32 MFMA, then vmcnt(6) + ONE barrier. Waves self-schedule
// within the K-tile -> LDS-read and MFMA overlap across waves instead of
// serializing behind per-phase barriers.
template <int BM, int BN, int K, bool ACCUM>
__global__ __launch_bounds__(512, 2)
void gemm_nt(const unsigned short* __restrict__ Ag,
             const unsigned short* __restrict__ Bg,
             float* __restrict__ C, int ldc, int beta) {
    constexpr int BSZ = (BM + BN) * 64;          // elements per K-tile buffer
    constexpr int NA  = BM / 64;                 // A gload issues per K-tile
    constexpr int NB  = BN / 64;                 // B gload issues per K-tile
    constexpr int NT  = K / 64;
    static_assert(NA + NB == 6, "6 issues/K-tile assumed by vmcnt(6)");
    __shared__ __align__(16) unsigned short lds[3 * BSZ];   // 144 KiB

    const int tid  = threadIdx.x;
    const int wave = tid >> 6, lane = tid & 63;
    const int mr = lane & 15, q = lane >> 4;
    const int srow = tid >> 3, sslot = tid & 7;       // staging row/slot
    const int wm = (BM >= BN) ? (wave >> 1) * 64 : (wave & 1) * 64;
    const int wn = (BM >= BN) ? (wave & 1) * 64 : (wave >> 1) * 64;

    // XCD-chunked block swizzle (nwg == 256, divisible by 8 -> bijective)
    const int gx   = gridDim.x;
    const int nwg  = gx * gridDim.y;
    const int flat = blockIdx.y * gx + blockIdx.x;
    const int swz  = (flat & 7) * (nwg >> 3) + (flat >> 3);
    const int m0   = (swz % gx) * BM;
    const int n0   = (swz / gx) * BN;

    const char* aG = (const char*)Ag;
    const char* bG = (const char*)Bg;
    const int ssw = (sslot ^ (srow & 7)) * 16;        // pre-swizzled src slot
    size_t aoff[NA], boff[NB];
#pragma unroll
    for (int j = 0; j < NA; ++j)
        aoff[j] = (size_t)(m0 + j * 64 + srow) * (LDK * 2) + ssw;
#pragma unroll
    for (int j = 0; j < NB; ++j)
        boff[j] = (size_t)(n0 + j * 64 + srow) * (LDK * 2) + ssw;

    unsigned short* bufC  = lds;
    unsigned short* bufN  = lds + BSZ;
    unsigned short* bufN2 = lds + 2 * BSZ;

    // issue idx in [0,6): first NA are A-halves, rest B-halves
    auto stage = [&](int idx, unsigned short* buf, size_t kB) {
        if (idx < NA)
            gload16(aG + aoff[idx] + kB, buf + idx * 4096 + wave * 512);
        else
            gload16(bG + boff[idx - NA] + kB,
                    buf + BM * 64 + (idx - NA) * 4096 + wave * 512);
    };

    f32x4 acc[4][4];
#pragma unroll
    for (int a = 0; a < 4; ++a)
#pragma unroll
        for (int b = 0; b < 4; ++b) acc[a][b] = (f32x4){0.f, 0.f, 0.f, 0.f};

    // prologue: tiles 0 and 1 in flight, wait tile 0 only (vmcnt(6))
#pragma unroll
    for (int i = 0; i < 6; ++i) stage(i, bufC, 0);
#pragma unroll
    for (int i = 0; i < 6; ++i) stage(i, bufN, 128);
    asm volatile("s_waitcnt vmcnt(6)" ::: "memory");
    __builtin_amdgcn_s_barrier();
    __builtin_amdgcn_sched_barrier(0);

    size_t kPre = 256;                 // byte k-offset of tile kt+2
#pragma unroll 1
    for (int kt = 0; kt < NT; ++kt) {
        const bool pf = (kt + 2 < NT);
        // all 16 fragment loads for both k-slices of this K-tile (proven-fast
        // order: ds_reads issued before the gload_lds of this iteration)
        bf16x8 af[2][4], bfr[2][4];
#pragma unroll
        for (int kk = 0; kk < 2; ++kk) {
#pragma unroll
            for (int mi = 0; mi < 4; ++mi) {
                int m = wm + mi * 16 + mr;
                af[kk][mi] = *(const bf16x8*)(bufC + m * 64 +
                                              (((kk * 4 + q) ^ (m & 7)) * 8));
            }
#pragma unroll
            for (int ni = 0; ni < 4; ++ni) {
                int n = wn + ni * 16 + mr;
                bfr[kk][ni] = *(const bf16x8*)(bufC + BM * 64 + n * 64 +
                                               (((kk * 4 + q) ^ (n & 7)) * 8));
            }
        }
        // prefetch tile kt+2 (issued now; waited only at end of NEXT iter)
        if (pf) {
#pragma unroll
            for (int i = 0; i < 6; ++i) stage(i, bufN2, kPre);
        }
        // 32 MFMAs; compiler interleaves with counted lgkmcnt against the
        // ds_reads above (m97-verified behavior), no barrier in between.
        __builtin_amdgcn_s_setprio(1);
#pragma unroll
        for (int kk = 0; kk < 2; ++kk)
#pragma unroll
            for (int mi = 0; mi < 4; ++mi)
#pragma unroll
                for (int ni = 0; ni < 4; ++ni)
                    acc[mi][ni] = __builtin_amdgcn_mfma_f32_16x16x32_bf16(
                        af[kk][mi], bfr[kk][ni], acc[mi][ni], 0, 0, 0);
        __builtin_amdgcn_s_setprio(0);
        // end-of-tile wait: tile kt+1's loads must have landed; tile kt+2's 6
        // stay in flight (counted, never 0 mid-loop). ONE barrier per K-tile:
        // protects next iter's overwrite of bufN2 (last read in iter kt-1,
        // whose ds_reads completed before that iter's MFMAs -> before barrier).
        if (pf)                    asm volatile("s_waitcnt vmcnt(6)" ::: "memory");
        else if (kt + 1 < NT)      asm volatile("s_waitcnt vmcnt(0)" ::: "memory");
        __builtin_amdgcn_s_barrier();
        __builtin_amdgcn_sched_barrier(0);
        unsigned short* t = bufC; bufC = bufN; bufN = bufN2; bufN2 = t;
        kPre += 128;
    }

    // C/D layout: col = lane&15, row = (lane>>4)*4 + reg
#pragma unroll
    for (int mi = 0; mi < 4; ++mi)
#pragma unroll
        for (int ni = 0; ni < 4; ++ni)
#pragma unroll
            for (int r = 0; r < 4; ++r) {
                int m = m0 + wm + mi * 16 + q * 4 + r;
                int n = n0 + wn + ni * 16 + mr;
                size_t off = (size_t)m * ldc + n;
                float v = acc[mi][ni][r];
                if (ACCUM) { if (beta) v += C[off]; }
                C[off] = v;
            }
}

// ---------------- MT fp32 -> bf16 ----------------
__global__ __launch_bounds__(256)
void cvt(const float* __restrict__ src, unsigned short* __restrict__ dst) {
    int idx = blockIdx.x * 256 + threadIdx.x;
    float4 v = ((const float4*)src)[idx];
    ushort4 o;
    o.x = f2bf(v.x); o.y = f2bf(v.y); o.z = f2bf(v.z); o.w = f2bf(v.w);
    ((ushort4*)dst)[idx] = o;
}

// ---------------- epilogue: re/im, row norm, scale (in place on d_out) ----
__global__ __launch_bounds__(256)
void epi(float* __restrict__ out, const float* __restrict__ pts,
         const float* __restrict__ A) {
    int n = blockIdx.x;
    int t = threadIdx.x;
    float x0 = pts[n * 3 + 0], x1 = pts[n * 3 + 1], x2 = pts[n * 3 + 2];
    float* row = out + (size_t)n * JD;
    float reA[2], imA[2];
    float ssum = 0.f;
#pragma unroll
    for (int u = 0; u < 2; ++u) {
        int j = t + u * 256;
        float pa = (x0 * A[j] + x1 * A[ENC + j] + x2 * A[2 * ENC + j]) * INV_R;
        float s, c;
        sincos_rev(pa, &s, &c);
        float gc = row[j], gs = row[ENC + j];
        float re = gc * c + gs * s;
        float im = gs * c - gc * s;
        reA[u] = re; imA[u] = im;
        ssum += re * re + im * im;
    }
#pragma unroll
    for (int off = 32; off > 0; off >>= 1) ssum += __shfl_down(ssum, off);
    __shared__ float red[4];
    if ((t & 63) == 0) red[t >> 6] = ssum;
    __syncthreads();
    float tot = red[0] + red[1] + red[2] + red[3];
    float scale = SQRT_D / sqrtf(tot);
#pragma unroll
    for (int u = 0; u < 2; ++u) {
        int j = t + u * 256;
        row[j]       = reA[u] * scale;
        row[ENC + j] = imA[u] * scale;
    }
}

extern "C" void kernel_launch(void* const* d_in, const int* in_sizes, int n_in,
                              void* d_out, int out_size, void* d_ws, size_t ws_size,
                              hipStream_t stream) {
    const float* pts = (const float*)d_in[0];
    const float* A   = (const float*)d_in[1];
    const float* B   = (const float*)d_in[2];
    float* out = (float*)d_out;
    char* ws = (char*)d_ws;

    // ws layout (192 MiB total):
    //   [0, 16M)          eAT  [1024][8192] bf16   (phase A)  / eB [8192][8192] (phase C, spans both)
    //   [16M, 151M)       eBT  [8192][8192] bf16   (phase A)
    //   [151M, 183M)      MTf  [1024][8192] fp32
    //   [183M, 199M)      MTb  [1024][8192] bf16
    unsigned short* eAT = (unsigned short*)ws;
    unsigned short* eBT = (unsigned short*)(ws + (size_t)JD * CH * 2);
    unsigned short* eBw = (unsigned short*)ws;
    size_t offMT = (size_t)(JD + ID) * CH * 2;
    float* MTf = (float*)(ws + offMT);
    unsigned short* MTb = (unsigned short*)(ws + offMT + (size_t)JD * ID * 4);

    for (int c = 0; c < NCH; ++c) {
        gen_t<<<dim3(73728), 256, 0, stream>>>(pts, A, B, eAT, eBT, c * CH);
        // MT[j][i] += eAT[j][:] . eBT[i][:]   (M=1024, N=8192 -> 8x32=256 WGs)
        gemm_nt<128, 256, CH, true><<<dim3(8, 32), 512, 0, stream>>>(
            eAT, eBT, MTf, ID, c);
    }
    cvt<<<dim3(8192), 256, 0, stream>>>(MTf, MTb);
    for (int c = 0; c < NCH; ++c) {
        gen_b<<<dim3(65536), 256, 0, stream>>>(pts, B, eBw, c * CH);
        // G[ln][j] = eB[ln][:] . MTb[j][:]    (M=8192, N=1024 -> 32x8=256 WGs)
        gemm_nt<256, 128, ID, false><<<dim3(32, 8), 512, 0, stream>>>(
            eBw, MTb, out + (size_t)c * CH * JD, JD, 0);
    }
    epi<<<dim3(NPTS), 256, 0, stream>>>(out, pts, A);
}